// Round 6
// baseline (1231.036 us; speedup 1.0000x reference)
//
#include <hip/hip_runtime.h>

// RNN: h_t = tanh(x[b,t]*W_ih + b_ih + b_hh + h_{t-1} @ W_hh^T), out = h_T @ W_out^T + b_out
// B=256 T=2048 H=256 P=24, fp32. One WG/batch (256 WGs = 256 CUs), 512 thr, 8 waves.
//
// Round-16: WHOLE-LOOP INLINE ASM. R12-R15 evidence: VGPR_Count pinned at 84
// regardless of launch bounds / waves_per_eu / per-op asm constraints; measured
// VALU busy (~790 cyc/SIMD/step) is ~275 cyc above the 512-cyc FMA floor +
// hand-counted misc, consistent with the allocator stashing w2 in AGPRs and
// paying v_accvgpr_read moves per step. Source-level control failed 3x ->
// take the register file by force: the entire 2048-step loop is one asm
// volatile block; weights live in clobber-forced arch VGPRs v[64:191].
//  - 128 scalar v_fma_f32 (even-k chain == old acc.x, odd-k == acc.y ->
//    bit-identical); ds_read_b128 x4 with lgkmcnt(3/2/1/0) interleave.
//  - butterfly via ds_swizzle_b32 xor-masks 0x201F/0x1C1F/0x081F/0x041F ==
//    same permutations as DPP 0x128/0x141/0x4E/0xB1 -> bit-identical sums.
//  - tanh: same v_mul(0x4038AA3B), v_exp_f32, +1.0, v_rcp_f32, fma(-2,.,1)
//    sequence; s_nop 3 after trans ops (gfx95x trans-use hazard guard).
//  - x: s_load_dwordx16 once per 16 steps in an lgkm-quiet window so the
//    in-step DS waitcnt counts are exact; xt consumed from SGPRs (s24-s39).
//  - raw "s_waitcnt lgkmcnt(0); s_barrier" per step (no vmcnt drain).
// Prediction: VGPR_Count ~210 (clobber-forced). If the AGPR-move model is
// right: ~700-780 us. If not: ~950-1250 us and the theory is settled.
// Locked-in: slot->row map m={0,2,7,5,8,10,15,13}; lane finalizes row
// 8g+(c>>1); one barrier/step; HSTR=20 padding; h0=0 init + final head in C++.

#define BB 256
#define TT 2048
#define HH 256
#define PP 24
#define HSTR 20   // h chunk stride: 16 data + 4 pad floats

__device__ __forceinline__ int hidx(int k) { return (k >> 4) * HSTR + (k & 15); }

// One recurrence step, fully scheduled by hand.
// RD = lds byte addr of this lane's h chunk (read buf), WR = lds byte addr of
// finalized row slot (write buf), XS = SGPR holding x_t for this step.
#define STEP(RD, WR, XS) \
  "ds_read_b128 v[48:51], " RD "\n" \
  "ds_read_b128 v[52:55], " RD " offset:16\n" \
  "ds_read_b128 v[56:59], " RD " offset:32\n" \
  "ds_read_b128 v[60:63], " RD " offset:48\n" \
  "s_waitcnt lgkmcnt(3)\n" \
  "v_mul_f32 v32, v64, v48\n"  "v_mul_f32 v40, v65, v49\n" \
  "v_mul_f32 v33, v80, v48\n"  "v_mul_f32 v41, v81, v49\n" \
  "v_mul_f32 v34, v96, v48\n"  "v_mul_f32 v42, v97, v49\n" \
  "v_mul_f32 v35, v112, v48\n" "v_mul_f32 v43, v113, v49\n" \
  "v_mul_f32 v36, v128, v48\n" "v_mul_f32 v44, v129, v49\n" \
  "v_mul_f32 v37, v144, v48\n" "v_mul_f32 v45, v145, v49\n" \
  "v_mul_f32 v38, v160, v48\n" "v_mul_f32 v46, v161, v49\n" \
  "v_mul_f32 v39, v176, v48\n" "v_mul_f32 v47, v177, v49\n" \
  "v_fma_f32 v32, v66, v50, v32\n"  "v_fma_f32 v40, v67, v51, v40\n" \
  "v_fma_f32 v33, v82, v50, v33\n"  "v_fma_f32 v41, v83, v51, v41\n" \
  "v_fma_f32 v34, v98, v50, v34\n"  "v_fma_f32 v42, v99, v51, v42\n" \
  "v_fma_f32 v35, v114, v50, v35\n" "v_fma_f32 v43, v115, v51, v43\n" \
  "v_fma_f32 v36, v130, v50, v36\n" "v_fma_f32 v44, v131, v51, v44\n" \
  "v_fma_f32 v37, v146, v50, v37\n" "v_fma_f32 v45, v147, v51, v45\n" \
  "v_fma_f32 v38, v162, v50, v38\n" "v_fma_f32 v46, v163, v51, v46\n" \
  "v_fma_f32 v39, v178, v50, v39\n" "v_fma_f32 v47, v179, v51, v47\n" \
  "s_waitcnt lgkmcnt(2)\n" \
  "v_fma_f32 v32, v68, v52, v32\n"  "v_fma_f32 v40, v69, v53, v40\n" \
  "v_fma_f32 v33, v84, v52, v33\n"  "v_fma_f32 v41, v85, v53, v41\n" \
  "v_fma_f32 v34, v100, v52, v34\n" "v_fma_f32 v42, v101, v53, v42\n" \
  "v_fma_f32 v35, v116, v52, v35\n" "v_fma_f32 v43, v117, v53, v43\n" \
  "v_fma_f32 v36, v132, v52, v36\n" "v_fma_f32 v44, v133, v53, v44\n" \
  "v_fma_f32 v37, v148, v52, v37\n" "v_fma_f32 v45, v149, v53, v45\n" \
  "v_fma_f32 v38, v164, v52, v38\n" "v_fma_f32 v46, v165, v53, v46\n" \
  "v_fma_f32 v39, v180, v52, v39\n" "v_fma_f32 v47, v181, v53, v47\n" \
  "v_fma_f32 v32, v70, v54, v32\n"  "v_fma_f32 v40, v71, v55, v40\n" \
  "v_fma_f32 v33, v86, v54, v33\n"  "v_fma_f32 v41, v87, v55, v41\n" \
  "v_fma_f32 v34, v102, v54, v34\n" "v_fma_f32 v42, v103, v55, v42\n" \
  "v_fma_f32 v35, v118, v54, v35\n" "v_fma_f32 v43, v119, v55, v43\n" \
  "v_fma_f32 v36, v134, v54, v36\n" "v_fma_f32 v44, v135, v55, v44\n" \
  "v_fma_f32 v37, v150, v54, v37\n" "v_fma_f32 v45, v151, v55, v45\n" \
  "v_fma_f32 v38, v166, v54, v38\n" "v_fma_f32 v46, v167, v55, v46\n" \
  "v_fma_f32 v39, v182, v54, v39\n" "v_fma_f32 v47, v183, v55, v47\n" \
  "s_waitcnt lgkmcnt(1)\n" \
  "v_fma_f32 v32, v72, v56, v32\n"  "v_fma_f32 v40, v73, v57, v40\n" \
  "v_fma_f32 v33, v88, v56, v33\n"  "v_fma_f32 v41, v89, v57, v41\n" \
  "v_fma_f32 v34, v104, v56, v34\n" "v_fma_f32 v42, v105, v57, v42\n" \
  "v_fma_f32 v35, v120, v56, v35\n" "v_fma_f32 v43, v121, v57, v43\n" \
  "v_fma_f32 v36, v136, v56, v36\n" "v_fma_f32 v44, v137, v57, v44\n" \
  "v_fma_f32 v37, v152, v56, v37\n" "v_fma_f32 v45, v153, v57, v45\n" \
  "v_fma_f32 v38, v168, v56, v38\n" "v_fma_f32 v46, v169, v57, v46\n" \
  "v_fma_f32 v39, v184, v56, v39\n" "v_fma_f32 v47, v185, v57, v47\n" \
  "v_fma_f32 v32, v74, v58, v32\n"  "v_fma_f32 v40, v75, v59, v40\n" \
  "v_fma_f32 v33, v90, v58, v33\n"  "v_fma_f32 v41, v91, v59, v41\n" \
  "v_fma_f32 v34, v106, v58, v34\n" "v_fma_f32 v42, v107, v59, v42\n" \
  "v_fma_f32 v35, v122, v58, v35\n" "v_fma_f32 v43, v123, v59, v43\n" \
  "v_fma_f32 v36, v138, v58, v36\n" "v_fma_f32 v44, v139, v59, v44\n" \
  "v_fma_f32 v37, v154, v58, v37\n" "v_fma_f32 v45, v155, v59, v45\n" \
  "v_fma_f32 v38, v170, v58, v38\n" "v_fma_f32 v46, v171, v59, v46\n" \
  "v_fma_f32 v39, v186, v58, v39\n" "v_fma_f32 v47, v187, v59, v47\n" \
  "s_waitcnt lgkmcnt(0)\n" \
  "v_fma_f32 v32, v76, v60, v32\n"  "v_fma_f32 v40, v77, v61, v40\n" \
  "v_fma_f32 v33, v92, v60, v33\n"  "v_fma_f32 v41, v93, v61, v41\n" \
  "v_fma_f32 v34, v108, v60, v34\n" "v_fma_f32 v42, v109, v61, v42\n" \
  "v_fma_f32 v35, v124, v60, v35\n" "v_fma_f32 v43, v125, v61, v43\n" \
  "v_fma_f32 v36, v140, v60, v36\n" "v_fma_f32 v44, v141, v61, v44\n" \
  "v_fma_f32 v37, v156, v60, v37\n" "v_fma_f32 v45, v157, v61, v45\n" \
  "v_fma_f32 v38, v172, v60, v38\n" "v_fma_f32 v46, v173, v61, v46\n" \
  "v_fma_f32 v39, v188, v60, v39\n" "v_fma_f32 v47, v189, v61, v47\n" \
  "v_fma_f32 v32, v78, v62, v32\n"  "v_fma_f32 v40, v79, v63, v40\n" \
  "v_fma_f32 v33, v94, v62, v33\n"  "v_fma_f32 v41, v95, v63, v41\n" \
  "v_fma_f32 v34, v110, v62, v34\n" "v_fma_f32 v42, v111, v63, v42\n" \
  "v_fma_f32 v35, v126, v62, v35\n" "v_fma_f32 v43, v127, v63, v43\n" \
  "v_fma_f32 v36, v142, v62, v36\n" "v_fma_f32 v44, v143, v63, v44\n" \
  "v_fma_f32 v37, v158, v62, v37\n" "v_fma_f32 v45, v159, v63, v45\n" \
  "v_fma_f32 v38, v174, v62, v38\n" "v_fma_f32 v46, v175, v63, v46\n" \
  "v_fma_f32 v39, v190, v62, v39\n" "v_fma_f32 v47, v191, v63, v47\n" \
  /* aa[s] = accX + accY  (== old acc.x + acc.y) */ \
  "v_add_f32 v24, v32, v40\n" "v_add_f32 v25, v33, v41\n" \
  "v_add_f32 v26, v34, v42\n" "v_add_f32 v27, v35, v43\n" \
  "v_add_f32 v28, v36, v44\n" "v_add_f32 v29, v37, v45\n" \
  "v_add_f32 v30, v38, v46\n" "v_add_f32 v31, v39, v47\n" \
  /* butterfly: xor8, xor7, xor2, xor1 (same perms as DPP version) */ \
  "ds_swizzle_b32 v33, v28 offset:0x201F\n" \
  "ds_swizzle_b32 v34, v29 offset:0x201F\n" \
  "ds_swizzle_b32 v35, v30 offset:0x201F\n" \
  "ds_swizzle_b32 v36, v31 offset:0x201F\n" \
  "s_waitcnt lgkmcnt(0)\n" \
  "v_add_f32 v24, v24, v33\n" "v_add_f32 v25, v25, v34\n" \
  "v_add_f32 v26, v26, v35\n" "v_add_f32 v27, v27, v36\n" \
  "ds_swizzle_b32 v33, v26 offset:0x1C1F\n" \
  "ds_swizzle_b32 v34, v27 offset:0x1C1F\n" \
  "s_waitcnt lgkmcnt(0)\n" \
  "v_add_f32 v24, v24, v33\n" "v_add_f32 v25, v25, v34\n" \
  "ds_swizzle_b32 v33, v25 offset:0x081F\n" \
  "s_waitcnt lgkmcnt(0)\n" \
  "v_add_f32 v24, v24, v33\n" \
  "ds_swizzle_b32 v33, v24 offset:0x041F\n" \
  "s_waitcnt lgkmcnt(0)\n" \
  "v_fma_f32 v25, " XS ", %[wih], %[cb]\n" \
  "v_add_f32 v24, v24, v33\n" \
  /* u = u0 + e ; tanh(u) = 1 - 2/(exp2(u*log2e*2)+1) */ \
  "v_add_f32 v24, v25, v24\n" \
  "v_mul_f32 v24, 0x4038aa3b, v24\n" \
  "v_exp_f32 v24, v24\n" \
  "s_nop 3\n" \
  "v_add_f32 v24, 1.0, v24\n" \
  "v_rcp_f32 v24, v24\n" \
  "s_nop 3\n" \
  "v_fma_f32 v24, -2.0, v24, 1.0\n" \
  "ds_write_b32 " WR ", v24\n" \
  "s_waitcnt lgkmcnt(0)\n" \
  "s_barrier\n"

__global__ __launch_bounds__(512, 1)
void rnn_persist(const float* __restrict__ x,
                 const float* __restrict__ W_ih,
                 const float* __restrict__ W_hh,
                 const float* __restrict__ b_ih,
                 const float* __restrict__ b_hh,
                 const float* __restrict__ W_out,
                 const float* __restrict__ b_out,
                 float* __restrict__ out)
{
    __shared__ __align__(16) float hbuf[2][16 * HSTR];   // 2 x 1.25 KB

    const int tid = threadIdx.x;
    const int b   = blockIdx.x;
    const int c   = tid & 15;    // K-chunk 0..15
    const int g   = tid >> 4;    // row group (rows 8g..8g+7)

    hbuf[0][hidx(tid & 255)] = 0.0f;   // h_0 = 0

    const int m[8] = {0, 2, 7, 5, 8, 10, 15, 13};

    // Per-slot weight byte offsets into W_hh (loaded inside the asm).
    unsigned woff[8];
    #pragma unroll
    for (int s = 0; s < 8; ++s) {
        const int row_idx = 8 * g + ((c ^ m[s]) >> 1);
        woff[s] = (unsigned)((row_idx * HH + 16 * c) * 4);
    }

    const int   o_fin = 8 * g + (c >> 1);
    const float wih   = W_ih[o_fin];
    const float cb    = b_ih[o_fin] + b_hh[o_fin];

    // LDS byte addresses (low 32 bits of the generic pointer = LDS offset).
    const unsigned rd0 = (unsigned)(uintptr_t)(&hbuf[0][c * HSTR]);
    const unsigned rd1 = (unsigned)(uintptr_t)(&hbuf[1][c * HSTR]);
    const unsigned wr0 = (unsigned)(uintptr_t)(&hbuf[0][hidx(o_fin)]);
    const unsigned wr1 = (unsigned)(uintptr_t)(&hbuf[1][hidx(o_fin)]);

    const float* xb = x + b * TT;

    __syncthreads();

    asm volatile(
        // ---- load all 128 weight floats into v[64:191] (arch, clobber-forced)
        "global_load_dwordx4 v[64:67],   %[o0], %[wb]\n"
        "global_load_dwordx4 v[68:71],   %[o0], %[wb] offset:16\n"
        "global_load_dwordx4 v[72:75],   %[o0], %[wb] offset:32\n"
        "global_load_dwordx4 v[76:79],   %[o0], %[wb] offset:48\n"
        "global_load_dwordx4 v[80:83],   %[o1], %[wb]\n"
        "global_load_dwordx4 v[84:87],   %[o1], %[wb] offset:16\n"
        "global_load_dwordx4 v[88:91],   %[o1], %[wb] offset:32\n"
        "global_load_dwordx4 v[92:95],   %[o1], %[wb] offset:48\n"
        "global_load_dwordx4 v[96:99],   %[o2], %[wb]\n"
        "global_load_dwordx4 v[100:103], %[o2], %[wb] offset:16\n"
        "global_load_dwordx4 v[104:107], %[o2], %[wb] offset:32\n"
        "global_load_dwordx4 v[108:111], %[o2], %[wb] offset:48\n"
        "global_load_dwordx4 v[112:115], %[o3], %[wb]\n"
        "global_load_dwordx4 v[116:119], %[o3], %[wb] offset:16\n"
        "global_load_dwordx4 v[120:123], %[o3], %[wb] offset:32\n"
        "global_load_dwordx4 v[124:127], %[o3], %[wb] offset:48\n"
        "global_load_dwordx4 v[128:131], %[o4], %[wb]\n"
        "global_load_dwordx4 v[132:135], %[o4], %[wb] offset:16\n"
        "global_load_dwordx4 v[136:139], %[o4], %[wb] offset:32\n"
        "global_load_dwordx4 v[140:143], %[o4], %[wb] offset:48\n"
        "global_load_dwordx4 v[144:147], %[o5], %[wb]\n"
        "global_load_dwordx4 v[148:151], %[o5], %[wb] offset:16\n"
        "global_load_dwordx4 v[152:155], %[o5], %[wb] offset:32\n"
        "global_load_dwordx4 v[156:159], %[o5], %[wb] offset:48\n"
        "global_load_dwordx4 v[160:163], %[o6], %[wb]\n"
        "global_load_dwordx4 v[164:167], %[o6], %[wb] offset:16\n"
        "global_load_dwordx4 v[168:171], %[o6], %[wb] offset:32\n"
        "global_load_dwordx4 v[172:175], %[o6], %[wb] offset:48\n"
        "global_load_dwordx4 v[176:179], %[o7], %[wb]\n"
        "global_load_dwordx4 v[180:183], %[o7], %[wb] offset:16\n"
        "global_load_dwordx4 v[184:187], %[o7], %[wb] offset:32\n"
        "global_load_dwordx4 v[188:191], %[o7], %[wb] offset:48\n"
        "s_mov_b64 s[16:17], %[xp]\n"
        "s_movk_i32 s20, 0x80\n"
        "s_waitcnt vmcnt(0)\n"
        "L_outer_%=:\n"
        // 16 x-values for the next 16 steps; lgkm-quiet window.
        "s_load_dwordx16 s[24:39], s[16:17], 0x0\n"
        "s_add_u32 s16, s16, 64\n"
        "s_addc_u32 s17, s17, 0\n"
        "s_waitcnt lgkmcnt(0)\n"
        "s_movk_i32 s22, 4\n"
        "L_inner_%=:\n"
        STEP("%[r0]", "%[w1]", "s24")
        STEP("%[r1]", "%[w0]", "s25")
        STEP("%[r0]", "%[w1]", "s26")
        STEP("%[r1]", "%[w0]", "s27")
        // shift next 4 x-values into s24..s27
        "s_mov_b64 s[24:25], s[28:29]\n"
        "s_mov_b64 s[26:27], s[30:31]\n"
        "s_mov_b64 s[28:29], s[32:33]\n"
        "s_mov_b64 s[30:31], s[34:35]\n"
        "s_mov_b64 s[32:33], s[36:37]\n"
        "s_mov_b64 s[34:35], s[38:39]\n"
        "s_sub_u32 s22, s22, 1\n"
        "s_cmp_lg_u32 s22, 0\n"
        "s_cbranch_scc1 L_inner_%=\n"
        "s_sub_u32 s20, s20, 1\n"
        "s_cmp_lg_u32 s20, 0\n"
        "s_cbranch_scc1 L_outer_%=\n"
        :
        : [o0]"v"(woff[0]), [o1]"v"(woff[1]), [o2]"v"(woff[2]), [o3]"v"(woff[3]),
          [o4]"v"(woff[4]), [o5]"v"(woff[5]), [o6]"v"(woff[6]), [o7]"v"(woff[7]),
          [r0]"v"(rd0), [r1]"v"(rd1), [w0]"v"(wr0), [w1]"v"(wr1),
          [wih]"v"(wih), [cb]"v"(cb),
          [wb]"s"(W_hh), [xp]"s"(xb)
        : "memory", "scc",
          "s16","s17","s20","s22",
          "s24","s25","s26","s27","s28","s29","s30","s31",
          "s32","s33","s34","s35","s36","s37","s38","s39",
          "v24","v25","v26","v27","v28","v29","v30","v31",
          "v32","v33","v34","v35","v36","v37","v38","v39",
          "v40","v41","v42","v43","v44","v45","v46","v47",
          "v48","v49","v50","v51","v52","v53","v54","v55",
          "v56","v57","v58","v59","v60","v61","v62","v63",
          "v64","v65","v66","v67","v68","v69","v70","v71",
          "v72","v73","v74","v75","v76","v77","v78","v79",
          "v80","v81","v82","v83","v84","v85","v86","v87",
          "v88","v89","v90","v91","v92","v93","v94","v95",
          "v96","v97","v98","v99","v100","v101","v102","v103",
          "v104","v105","v106","v107","v108","v109","v110","v111",
          "v112","v113","v114","v115","v116","v117","v118","v119",
          "v120","v121","v122","v123","v124","v125","v126","v127",
          "v128","v129","v130","v131","v132","v133","v134","v135",
          "v136","v137","v138","v139","v140","v141","v142","v143",
          "v144","v145","v146","v147","v148","v149","v150","v151",
          "v152","v153","v154","v155","v156","v157","v158","v159",
          "v160","v161","v162","v163","v164","v165","v166","v167",
          "v168","v169","v170","v171","v172","v173","v174","v175",
          "v176","v177","v178","v179","v180","v181","v182","v183",
          "v184","v185","v186","v187","v188","v189","v190","v191"
    );

    __syncthreads();

    // Head: h_T in hbuf[0] (2048 steps, even). out[b,p] = b_out[p] + W_out[p,:].h_T
    if (tid < PP) {
        const float* wo = W_out + tid * HH;
        float s0 = 0.f, s1 = 0.f, s2 = 0.f, s3 = 0.f;
        #pragma unroll
        for (int h = 0; h < HH; h += 4) {
            s0 = fmaf(wo[h + 0], hbuf[0][hidx(h + 0)], s0);
            s1 = fmaf(wo[h + 1], hbuf[0][hidx(h + 1)], s1);
            s2 = fmaf(wo[h + 2], hbuf[0][hidx(h + 2)], s2);
            s3 = fmaf(wo[h + 3], hbuf[0][hidx(h + 3)], s3);
        }
        out[b * PP + tid] = b_out[tid] + (s0 + s1) + (s2 + s3);
    }
}

extern "C" void kernel_launch(void* const* d_in, const int* in_sizes, int n_in,
                              void* d_out, int out_size, void* d_ws, size_t ws_size,
                              hipStream_t stream) {
    const float* x     = (const float*)d_in[0];
    const float* W_ih  = (const float*)d_in[1];
    const float* W_hh  = (const float*)d_in[2];
    const float* b_ih  = (const float*)d_in[3];
    const float* b_hh  = (const float*)d_in[4];
    const float* W_out = (const float*)d_in[5];
    const float* b_out = (const float*)d_in[6];
    float* out = (float*)d_out;

    rnn_persist<<<BB, 512, 0, stream>>>(x, W_ih, W_hh, b_ih, b_hh, W_out, b_out, out);
}

// Round 8
// 1133.968 us; speedup vs baseline: 1.0856x; 1.0856x over previous
//
#include <hip/hip_runtime.h>

// RNN: h_t = tanh(x[b,t]*W_ih + b_ih + b_hh + h_{t-1} @ W_hh^T), out = h_T @ W_out^T + b_out
// B=256 T=2048 H=256 P=24, fp32. One WG/batch (256 WGs = 256 CUs), 512 thr, 8 waves.
//
// Round-18: R7 retry with compiler-managed permlane32_swap. R7's absmax=1.9
// was the hand-asm xhalf_sum: v_mov immediately followed by the crosslane
// v_permlane32_swap inside one asm block -> VALU->DPP read hazard that the
// compiler normally pads with wait-states, bypassed by raw asm -> stale reads.
// Fix: __builtin_amdgcn_permlane32_swap (compiler inserts hazard padding);
// __shfl_xor(e,32,64) fallback if the builtin is missing. Same lane-invariant
// FP order (lo+hi on every lane) -> dup-write safety preserved.
// Structure (unchanged from R7, actually under test this round): 16 rows x
// 8 cols per lane (was 8x16): each lane reads 32B (2 ds_read_b128, was 4) ->
// post-barrier DS convoy halves (16 reads/CU); FMAs start at lgkmcnt(1).
// Two banks of the PROVEN 8-slot fused DPP butterfly (m={0,2,7,5,8,10,15,13});
// col-halves combined in-VALU via permlane32_swap (no DS round-trip -- R6's
// serial-swizzle mistake stays dead). Lane layout: L=tid&63 =
// (d4<<5)|(r0<<4)|c4; r=2*wave+r0 (16 row-grps of 16); d=16*d4+c4 (32
// col-chunks of 8). Lane finalizes row 16r+8*d4+(c4>>1); 2-way same-addr
// writes, identical bits. Reduction re-associated vs R12 -> absmax moves
// within ~1e-3 (threshold 2.4e-2).
// Locked-in: j-outer FMA; one barrier/step; HSTR=20; x block-prefetch;
// DPP butterfly in-VALU; launch_bounds(512,1).

#define BB 256
#define TT 2048
#define HH 256
#define PP 24
#define HSTR 20   // h chunk stride: 16 data + 4 pad floats

typedef float v2f __attribute__((ext_vector_type(2)));
typedef int   v2i __attribute__((ext_vector_type(2)));

struct alignas(16) hquad { v2f lo, hi; };   // one ds_read_b128

__device__ __forceinline__ int hidx(int k) { return (k >> 4) * HSTR + (k & 15); }

template<int CTRL>
__device__ __forceinline__ float dppadd(float dst, float src) {
    return dst + __int_as_float(__builtin_amdgcn_update_dpp(
        0, __float_as_int(src), CTRL, 0xf, 0xf, true));
}

// Cross-32 combine: every lane returns lowhalf + highhalf (same FP order on
// all lanes -> identical bits). Compiler-managed intrinsic handles the
// VALU->crosslane hazard padding that R7's raw asm omitted.
__device__ __forceinline__ float xhalf_sum(float e) {
#if __has_builtin(__builtin_amdgcn_permlane32_swap)
    const int ei = __float_as_int(e);
    v2i pr = __builtin_amdgcn_permlane32_swap(ei, ei, false, false);
    // pr.x = [e_lo | e_lo], pr.y = [e_hi | e_hi]
    return __int_as_float(pr.x) + __int_as_float(pr.y);
#else
    return e + __shfl_xor(e, 32, 64);
#endif
}

__global__ __launch_bounds__(512, 1)
void rnn_persist(const float* __restrict__ x,
                 const float* __restrict__ W_ih,
                 const float* __restrict__ W_hh,
                 const float* __restrict__ b_ih,
                 const float* __restrict__ b_hh,
                 const float* __restrict__ W_out,
                 const float* __restrict__ b_out,
                 float* __restrict__ out)
{
    __shared__ __align__(16) float hbuf[2][16 * HSTR];   // 2 x 1.25 KB

    const int tid = threadIdx.x;
    const int b   = blockIdx.x;
    const int L   = tid & 63;
    const int c4  = L & 15;          // butterfly lane (DPP row position)
    const int r0  = (L >> 4) & 1;    // row-group LSB
    const int d4  = L >> 5;          // col-half (permlane32 partner bit)
    const int r   = (tid >> 6) * 2 + r0;   // row group 0..15 (rows 16r..16r+15)
    const int d   = d4 * 16 + c4;          // col chunk 0..31 (cols 8d..8d+7)

    hbuf[0][hidx(tid & 255)] = 0.0f;   // h_0 = 0 (2-way same-addr, same value)

    // Slot->row permutation for the select-free butterfly (per bank).
    const int m[8] = {0, 2, 7, 5, 8, 10, 15, 13};

    // Weights: bank bk, slot s holds row 16r + 8bk + ((c4^m[s])>>1),
    // cols 8d..8d+7. 2*8*8 = 128 floats = 64 v2f.
    v2f w2[2][8][4];
    #pragma unroll
    for (int bk = 0; bk < 2; ++bk) {
        #pragma unroll
        for (int s = 0; s < 8; ++s) {
            const int row_idx = 16 * r + 8 * bk + ((c4 ^ m[s]) >> 1);
            const float* row = W_hh + row_idx * HH + 8 * d;
            const float4 qA = *(const float4*)(row);
            const float4 qB = *(const float4*)(row + 4);
            w2[bk][s][0] = (v2f){qA.x, qA.y};
            w2[bk][s][1] = (v2f){qA.z, qA.w};
            w2[bk][s][2] = (v2f){qB.x, qB.y};
            w2[bk][s][3] = (v2f){qB.z, qB.w};
        }
    }

    // Row this lane finalizes: o = 16r + 8*d4 + (c4>>1) (dup lanes agree).
    const int   o_fin = 16 * r + 8 * d4 + (c4 >> 1);
    const float wih   = W_ih[o_fin];
    const float cb    = b_ih[o_fin] + b_hh[o_fin];
    const int   widx  = hidx(o_fin);

    __syncthreads();

    // Lane's 8 h-floats: chunk d>>1, float offset 8*(d&1). 16B-aligned.
    const float* hc0 = hbuf[0] + (d >> 1) * HSTR + (d & 1) * 8;
    const float* hc1 = hbuf[1] + (d >> 1) * HSTR + (d & 1) * 8;
    const float* xb  = x + b * TT;   // uniform address stream -> s_load

    auto step = [&](const float* __restrict__ cur, float* __restrict__ nxt,
                    float xt) __attribute__((always_inline)) {
        const hquad* hq = (const hquad*)cur;
        // Two reads back-to-back; j-outer consumes qa first (lgkmcnt(1)).
        const hquad qa = hq[0], qb = hq[1];

        v2f acc0[8], acc1[8];
        #pragma unroll
        for (int s = 0; s < 8; ++s) acc0[s] = w2[0][s][0] * qa.lo;     // j=0
        #pragma unroll
        for (int s = 0; s < 8; ++s) acc1[s] = w2[1][s][0] * qa.lo;
        #pragma unroll
        for (int s = 0; s < 8; ++s)
            acc0[s] = __builtin_elementwise_fma(w2[0][s][1], qa.hi, acc0[s]);
        #pragma unroll
        for (int s = 0; s < 8; ++s)
            acc1[s] = __builtin_elementwise_fma(w2[1][s][1], qa.hi, acc1[s]);
        #pragma unroll
        for (int s = 0; s < 8; ++s)
            acc0[s] = __builtin_elementwise_fma(w2[0][s][2], qb.lo, acc0[s]);
        #pragma unroll
        for (int s = 0; s < 8; ++s)
            acc1[s] = __builtin_elementwise_fma(w2[1][s][2], qb.lo, acc1[s]);
        #pragma unroll
        for (int s = 0; s < 8; ++s)
            acc0[s] = __builtin_elementwise_fma(w2[0][s][3], qb.hi, acc0[s]);
        #pragma unroll
        for (int s = 0; s < 8; ++s)
            acc1[s] = __builtin_elementwise_fma(w2[1][s][3], qb.hi, acc1[s]);

        float aa0[8], aa1[8];
        #pragma unroll
        for (int s = 0; s < 8; ++s) aa0[s] = acc0[s].x + acc0[s].y;
        #pragma unroll
        for (int s = 0; s < 8; ++s) aa1[s] = acc1[s].x + acc1[s].y;

        // Bank-0 butterfly (rows 16r..16r+7 over this col-half).
        float b00 = dppadd<0x128>(aa0[0], aa0[4]);   // xor8
        float b01 = dppadd<0x128>(aa0[1], aa0[5]);
        float b02 = dppadd<0x128>(aa0[2], aa0[6]);
        float b03 = dppadd<0x128>(aa0[3], aa0[7]);
        float c00 = dppadd<0x141>(b00, b02);         // xor7
        float c01 = dppadd<0x141>(b01, b03);
        float d0  = dppadd<0x4E>(c00, c01);          // xor2
        float e0  = dppadd<0xB1>(d0, d0);            // xor1
        // Bank-1 butterfly (rows 16r+8..16r+15).
        float b10 = dppadd<0x128>(aa1[0], aa1[4]);
        float b11 = dppadd<0x128>(aa1[1], aa1[5]);
        float b12 = dppadd<0x128>(aa1[2], aa1[6]);
        float b13 = dppadd<0x128>(aa1[3], aa1[7]);
        float c10 = dppadd<0x141>(b10, b12);
        float c11 = dppadd<0x141>(b11, b13);
        float d1  = dppadd<0x4E>(c10, c11);
        float e1  = dppadd<0xB1>(d1, d1);

        // Cross-half combine (in-VALU permlane, no DS round-trip).
        const float full0 = xhalf_sum(e0);
        const float full1 = xhalf_sum(e1);
        const float e     = d4 ? full1 : full0;   // lane-constant select

        // tanh(u) = 1 - 2/(e^{2u}+1); exp2 saturates cleanly at large |u|.
        const float u  = fmaf(xt, wih, cb) + e;
        const float p  = __builtin_amdgcn_exp2f(u * 2.8853900817779268f);
        const float th = fmaf(-2.f, __builtin_amdgcn_rcpf(p + 1.f), 1.f);
        nxt[widx] = th;   // dup lanes write identical bits (same addr)
        __syncthreads();
    };

    // x block-prefetch: block's two float4s fetched one 8-step block ahead.
    float4 xa = *(const float4*)(xb + 0);
    float4 xc = *(const float4*)(xb + 4);
    for (int t = 0; t < TT; t += 8) {
        const int tn = (t + 8 < TT) ? (t + 8) : t;   // clamped (last block refetch)
        const float4 xa_n = *(const float4*)(xb + tn);
        const float4 xc_n = *(const float4*)(xb + tn + 4);
        step(hc0, hbuf[1], xa.x);
        step(hc1, hbuf[0], xa.y);
        step(hc0, hbuf[1], xa.z);
        step(hc1, hbuf[0], xa.w);
        step(hc0, hbuf[1], xc.x);
        step(hc1, hbuf[0], xc.y);
        step(hc0, hbuf[1], xc.z);
        step(hc1, hbuf[0], xc.w);
        xa = xa_n;
        xc = xc_n;
    }

    // Head: h_T in hbuf[0] (TT % 8 == 0). out[b,p] = b_out[p] + W_out[p,:].h_T
    if (tid < PP) {
        const float* wo = W_out + tid * HH;
        float s0 = 0.f, s1 = 0.f, s2 = 0.f, s3 = 0.f;
        #pragma unroll
        for (int h = 0; h < HH; h += 4) {
            s0 = fmaf(wo[h + 0], hbuf[0][hidx(h + 0)], s0);
            s1 = fmaf(wo[h + 1], hbuf[0][hidx(h + 1)], s1);
            s2 = fmaf(wo[h + 2], hbuf[0][hidx(h + 2)], s2);
            s3 = fmaf(wo[h + 3], hbuf[0][hidx(h + 3)], s3);
        }
        out[b * PP + tid] = b_out[tid] + (s0 + s1) + (s2 + s3);
    }
}

extern "C" void kernel_launch(void* const* d_in, const int* in_sizes, int n_in,
                              void* d_out, int out_size, void* d_ws, size_t ws_size,
                              hipStream_t stream) {
    const float* x     = (const float*)d_in[0];
    const float* W_ih  = (const float*)d_in[1];
    const float* W_hh  = (const float*)d_in[2];
    const float* b_ih  = (const float*)d_in[3];
    const float* b_hh  = (const float*)d_in[4];
    const float* W_out = (const float*)d_in[5];
    const float* b_out = (const float*)d_in[6];
    float* out = (float*)d_out;

    rnn_persist<<<BB, 512, 0, stream>>>(x, W_ih, W_hh, b_ih, b_hh, W_out, b_out, out);
}

// Round 10
// 967.809 us; speedup vs baseline: 1.2720x; 1.1717x over previous
//
#include <hip/hip_runtime.h>

// RNN: h_t = tanh(x[b,t]*W_ih + b_ih + b_hh + h_{t-1} @ W_hh^T), out = h_T @ W_out^T + b_out
// B=256 T=2048 H=256 P=24, fp32. One WG/batch (256 WGs = 256 CUs), 512 thr, 8 waves.
//
// Round-19 (resubmit; R9 bench was a GPUAcquisitionTimeout, no data):
// R12 structure + raw lgkm-only barrier.
// R8 post-mortem: the 16x8 split regressed via 33.5M bank conflicts
// (misaligned quads from the (d&1)*8 offset) + 19 extra butterfly VALU insts;
// and DS bytes are split-invariant (each wave streams all 256 h regardless),
// so that direction is dead even conflict-free. Revert to R12 (best, 967us).
// Cross-round busy-cycle model (R6/R8/R12/R13): VALU ~4cyc/inst -> step =
// 512 FMA floor + ~240 misc + ~440 stall. One unforced stall in R12:
// __syncthreads drains vmcnt(0) every step, so the x block-prefetch
// (global_load_dwordx4 issued right before the 8 steps) stalls the next
// barrier by L2/L3 latency on prefetch steps (~25-40 cyc/step avg).
// Fix: per-step barrier = asm "s_waitcnt lgkmcnt(0); s_barrier" -- only the
// ds_write ordering is needed; vmcnt never drains at barriers. Compiler
// still waits vmcnt at first USE of x values (8 steps after issue, free).
// Math identical to R12 -> absmax bit-identical 0.0001220703.
// Locked-in: j-outer FMA loop (FMAs start at lgkmcnt(3)); select-free DPP
// butterfly (slot s = row (c^m[s])>>1, m={0,2,7,5,8,10,15,13}; 8 fused
// v_add_f32_dpp); lane finalizes row 8g+(c>>1); all lanes write h (2-way
// same-addr free); one barrier/step; HSTR=20 padding; x block-prefetch.

#define BB 256
#define TT 2048
#define HH 256
#define PP 24
#define HSTR 20   // h chunk stride: 16 data + 4 pad floats

typedef float v2f __attribute__((ext_vector_type(2)));

struct alignas(16) hquad { v2f lo, hi; };   // one ds_read_b128

__device__ __forceinline__ int hidx(int k) { return (k >> 4) * HSTR + (k & 15); }

template<int CTRL>
__device__ __forceinline__ float dppadd(float dst, float src) {
    return dst + __int_as_float(__builtin_amdgcn_update_dpp(
        0, __float_as_int(src), CTRL, 0xf, 0xf, true));
}

// LDS-only barrier: waits for this wave's DS ops (the h-write) then syncs.
// Does NOT drain vmcnt -> the x block-prefetch global loads stay in flight
// across step barriers (compiler inserts its own vmcnt wait at first use).
__device__ __forceinline__ void lds_barrier() {
    asm volatile("s_waitcnt lgkmcnt(0)\n\ts_barrier" ::: "memory");
}

__global__ __launch_bounds__(512, 1)
void rnn_persist(const float* __restrict__ x,
                 const float* __restrict__ W_ih,
                 const float* __restrict__ W_hh,
                 const float* __restrict__ b_ih,
                 const float* __restrict__ b_hh,
                 const float* __restrict__ W_out,
                 const float* __restrict__ b_out,
                 float* __restrict__ out)
{
    __shared__ __align__(16) float hbuf[2][16 * HSTR];   // 2 x 1.25 KB

    const int tid = threadIdx.x;
    const int b   = blockIdx.x;
    const int c   = tid & 15;    // K-chunk 0..15 (DPP row lane)
    const int g   = tid >> 4;    // row group (rows 8g..8g+7)

    hbuf[0][hidx(tid & 255)] = 0.0f;   // h_0 = 0 (both halves write, same value)

    // Slot->row permutation for the select-free butterfly.
    const int m[8] = {0, 2, 7, 5, 8, 10, 15, 13};

    // Weights: slot s holds row 8g + ((c^m[s])>>1), cols 16c..16c+15. 128 regs.
    v2f w2[8][8];
    #pragma unroll
    for (int s = 0; s < 8; ++s) {
        const int row_idx = 8 * g + ((c ^ m[s]) >> 1);
        const float* row = W_hh + row_idx * HH + 16 * c;
        #pragma unroll
        for (int j = 0; j < 4; ++j) {
            const float4 q = *(const float4*)(row + 4 * j);
            w2[s][2 * j + 0] = (v2f){q.x, q.y};
            w2[s][2 * j + 1] = (v2f){q.z, q.w};
        }
    }

    // Row this lane finalizes: o = 8g + (c>>1) (both parities agree).
    const int   o_fin = 8 * g + (c >> 1);
    const float wih   = W_ih[o_fin];
    const float cb    = b_ih[o_fin] + b_hh[o_fin];
    const int   widx  = hidx(o_fin);

    __syncthreads();

    const float* hc0 = hbuf[0] + c * HSTR;
    const float* hc1 = hbuf[1] + c * HSTR;
    const float* xb  = x + b * TT;

    auto step = [&](const float* __restrict__ cur, float* __restrict__ nxt,
                    float xt) __attribute__((always_inline)) {
        const hquad* hq = (const hquad*)cur;
        // Issue all 4 reads back-to-back; consume in arrival order (j-outer)
        // so FMAs start at lgkmcnt(3).
        const hquad q0 = hq[0], q1 = hq[1], q2 = hq[2], q3 = hq[3];

        v2f acc[8];
        #pragma unroll
        for (int s = 0; s < 8; ++s) acc[s] = w2[s][0] * q0.lo;       // j=0
        #pragma unroll
        for (int s = 0; s < 8; ++s)
            acc[s] = __builtin_elementwise_fma(w2[s][1], q0.hi, acc[s]);
        #pragma unroll
        for (int s = 0; s < 8; ++s)
            acc[s] = __builtin_elementwise_fma(w2[s][2], q1.lo, acc[s]);
        #pragma unroll
        for (int s = 0; s < 8; ++s)
            acc[s] = __builtin_elementwise_fma(w2[s][3], q1.hi, acc[s]);
        #pragma unroll
        for (int s = 0; s < 8; ++s)
            acc[s] = __builtin_elementwise_fma(w2[s][4], q2.lo, acc[s]);
        #pragma unroll
        for (int s = 0; s < 8; ++s)
            acc[s] = __builtin_elementwise_fma(w2[s][5], q2.hi, acc[s]);
        #pragma unroll
        for (int s = 0; s < 8; ++s)
            acc[s] = __builtin_elementwise_fma(w2[s][6], q3.lo, acc[s]);
        #pragma unroll
        for (int s = 0; s < 8; ++s)
            acc[s] = __builtin_elementwise_fma(w2[s][7], q3.hi, acc[s]);

        float aa[8];
        #pragma unroll
        for (int s = 0; s < 8; ++s) aa[s] = acc[s].x + acc[s].y;

        // Select-free butterfly: 8 fused DPP adds, no cndmasks.
        float b0 = dppadd<0x128>(aa[0], aa[4]);   // xor8 (row_ror:8)
        float b1 = dppadd<0x128>(aa[1], aa[5]);
        float b2 = dppadd<0x128>(aa[2], aa[6]);
        float b3 = dppadd<0x128>(aa[3], aa[7]);
        float c0 = dppadd<0x141>(b0, b2);         // xor7 (row_half_mirror)
        float c1 = dppadd<0x141>(b1, b3);
        float d  = dppadd<0x4E>(c0, c1);          // xor2 (quad_perm 2,3,0,1)
        float e  = dppadd<0xB1>(d, d);            // xor1 (quad_perm 1,0,3,2)

        // tanh(u) = 1 - 2/(e^{2u}+1); exp2 saturates cleanly at large |u|.
        const float u  = fmaf(xt, wih, cb) + e;
        const float p  = __builtin_amdgcn_exp2f(u * 2.8853900817779268f);
        const float th = fmaf(-2.f, __builtin_amdgcn_rcpf(p + 1.f), 1.f);
        nxt[widx] = th;   // both parities write identical value (2-way, free)
        lds_barrier();    // lgkm-only: vmcnt (x prefetch) stays in flight
    };

    // x block-prefetch: block's two float4s fetched one 8-step block ahead.
    // With the lgkm-only barrier these loads are never drained mid-block.
    float4 xa = *(const float4*)(xb + 0);
    float4 xc = *(const float4*)(xb + 4);
    for (int t = 0; t < TT; t += 8) {
        const int tn = (t + 8 < TT) ? (t + 8) : t;   // clamped (last block refetch)
        const float4 xa_n = *(const float4*)(xb + tn);
        const float4 xc_n = *(const float4*)(xb + tn + 4);
        step(hc0, hbuf[1], xa.x);
        step(hc1, hbuf[0], xa.y);
        step(hc0, hbuf[1], xa.z);
        step(hc1, hbuf[0], xa.w);
        step(hc0, hbuf[1], xc.x);
        step(hc1, hbuf[0], xc.y);
        step(hc0, hbuf[1], xc.z);
        step(hc1, hbuf[0], xc.w);
        xa = xa_n;
        xc = xc_n;
    }

    // Head: h_T in hbuf[0] (TT % 8 == 0). out[b,p] = b_out[p] + W_out[p,:].h_T
    if (tid < PP) {
        const float* wo = W_out + tid * HH;
        float s0 = 0.f, s1 = 0.f, s2 = 0.f, s3 = 0.f;
        #pragma unroll
        for (int h = 0; h < HH; h += 4) {
            s0 = fmaf(wo[h + 0], hbuf[0][hidx(h + 0)], s0);
            s1 = fmaf(wo[h + 1], hbuf[0][hidx(h + 1)], s1);
            s2 = fmaf(wo[h + 2], hbuf[0][hidx(h + 2)], s2);
            s3 = fmaf(wo[h + 3], hbuf[0][hidx(h + 3)], s3);
        }
        out[b * PP + tid] = b_out[tid] + (s0 + s1) + (s2 + s3);
    }
}

extern "C" void kernel_launch(void* const* d_in, const int* in_sizes, int n_in,
                              void* d_out, int out_size, void* d_ws, size_t ws_size,
                              hipStream_t stream) {
    const float* x     = (const float*)d_in[0];
    const float* W_ih  = (const float*)d_in[1];
    const float* W_hh  = (const float*)d_in[2];
    const float* b_ih  = (const float*)d_in[3];
    const float* b_hh  = (const float*)d_in[4];
    const float* W_out = (const float*)d_in[5];
    const float* b_out = (const float*)d_in[6];
    float* out = (float*)d_out;

    rnn_persist<<<BB, 512, 0, stream>>>(x, W_ih, W_hh, b_ih, b_hh, W_out, b_out, out);
}